// Round 22
// baseline (1742.331 us; speedup 1.0000x reference)
//
#include <hip/hip_runtime.h>
#include <hip/hip_bf16.h>

#define NHW 6400
#define CIN 256
#define CIO 128
#define NB 2

typedef __bf16 bf16x8 __attribute__((ext_vector_type(8)));
typedef float f32x4 __attribute__((ext_vector_type(4)));

#define LOG2E 1.4426950408889634f
#define FSH (-20.0f * LOG2E)   // fixed logit shift, cancels exactly in softmax ratio

__device__ __forceinline__ unsigned short f2bfu(float x) {
    union { float f; unsigned u; } a; a.f = x;
    unsigned r = (a.u + 0x7fffu + ((a.u >> 16) & 1u)) >> 16;  // RNE
    return (unsigned short)r;
}
__device__ __forceinline__ float bfu2f(unsigned short v) {
    union { unsigned u; float f; } a; a.u = ((unsigned)v) << 16;
    return a.f;
}
__device__ __forceinline__ void splitbf(float v, unsigned short& h, unsigned short& l) {
    unsigned short hh = f2bfu(v);
    h = hh;
    l = f2bfu(v - bfu2f(hh));
}
// identical exp path in both passes: v_fma_f32 + v_exp_f32
__device__ __forceinline__ float pexp(float f) {
    return __builtin_amdgcn_exp2f(__builtin_fmaf(f, LOG2E, FSH));
}

#define MFMA(a, b, c) __builtin_amdgcn_mfma_f32_16x16x32_bf16((a), (b), (c), 0, 0, 0)

// async global->LDS, 16B per lane: per-lane global src, wave-uniform LDS base
typedef const __attribute__((address_space(1))) unsigned gu32;
typedef __attribute__((address_space(3))) unsigned lu32;
__device__ __forceinline__ void gload16(const void* g, void* l) {
    __builtin_amdgcn_global_load_lds((gu32*)g, (lu32*)l, 16, 0, 0);
}

// 16m f-chain (validated r13-r21): value at (lane l, reg r) =
// f[n = n0 + (l&15)][m = m0 + (l>>4)*4 + r]. Used by BOTH k_colsum and
// k_attn -> softmax numerator and denominator see bitwise-identical logits.
__device__ __forceinline__ void f16c(
    const unsigned short* __restrict__ ph_hi, const unsigned short* __restrict__ ph_lo,
    size_t a0, const bf16x8* tBh, const bf16x8* tBl, f32x4& f0)
{
    const f32x4 z4 = {0.f, 0.f, 0.f, 0.f};
    f0 = z4;
    #pragma unroll
    for (int kk = 0; kk < 4; ++kk) {
        bf16x8 Ah0 = *(const bf16x8*)(ph_hi + a0 + kk*32);
        bf16x8 Al0 = *(const bf16x8*)(ph_lo + a0 + kk*32);
        f0 = MFMA(Ah0, tBh[kk], f0);
        f0 = MFMA(Ah0, tBl[kk], f0);
        f0 = MFMA(Al0, tBh[kk], f0);
    }
}

// ---------------------------------------------------------------------------
// K0: zero Z
// ---------------------------------------------------------------------------
__global__ __launch_bounds__(256) void k_zero(float* __restrict__ Zp) {
    const int i = blockIdx.x * 256 + threadIdx.x;
    if (i < NB * NHW) Zp[i] = 0.0f;
}
// K0b: zero yT (atomic accumulation target)
__global__ __launch_bounds__(256) void k_zeroy(float* __restrict__ yT) {
    const size_t i = (size_t)blockIdx.x * 256 + threadIdx.x;  // covers NB*CIO*NHW/4
    float4 z = {0.f, 0.f, 0.f, 0.f};
    *(float4*)&yT[i * 4] = z;
}

// ---------------------------------------------------------------------------
// K1: three 1x1-conv projections (fp32 VALU, validated r5/r6/r11). theta/phi
// -> split-bf16 planes [b][n][ci] (carved from d_out); g -> fp32 [b][m][ci].
// ---------------------------------------------------------------------------
__global__ __launch_bounds__(256) void k_proj(
    const float* __restrict__ x,
    const float* __restrict__ gw, const float* __restrict__ gbias,
    const float* __restrict__ tw, const float* __restrict__ tbias,
    const float* __restrict__ pw, const float* __restrict__ pbias,
    unsigned short* __restrict__ th_hi, unsigned short* __restrict__ th_lo,
    unsigned short* __restrict__ ph_hi, unsigned short* __restrict__ ph_lo,
    float* __restrict__ g32)
{
    __shared__ float xT[16][260];
    const int n0 = blockIdx.x * 16;
    const int b  = blockIdx.y;
    const int t  = threadIdx.x;
    {
        const int nq = t & 3, cq = t >> 2;
        #pragma unroll
        for (int c0 = 0; c0 < 4; ++c0) {
            const int c = c0 * 64 + cq;
            float4 v = *(const float4*)&x[((size_t)b * CIN + c) * NHW + n0 + nq * 4];
            xT[nq*4+0][c] = v.x; xT[nq*4+1][c] = v.y;
            xT[nq*4+2][c] = v.z; xT[nq*4+3][c] = v.w;
        }
    }
    __syncthreads();
    const int ci = t & 127, nh = t >> 7;
    float aG[8], aT[8], aP[8];
    #pragma unroll
    for (int i = 0; i < 8; ++i) { aG[i]=0.f; aT[i]=0.f; aP[i]=0.f; }
    for (int c4 = 0; c4 < 64; ++c4) {
        float4 wg = *(const float4*)&gw[ci*CIN + c4*4];
        float4 wt = *(const float4*)&tw[ci*CIN + c4*4];
        float4 wp = *(const float4*)&pw[ci*CIN + c4*4];
        #pragma unroll
        for (int i = 0; i < 8; ++i) {
            float4 xv = *(const float4*)&xT[nh*8 + i][c4*4];
            aG[i] += wg.x*xv.x + wg.y*xv.y + wg.z*xv.z + wg.w*xv.w;
            aT[i] += wt.x*xv.x + wt.y*xv.y + wt.z*xv.z + wt.w*xv.w;
            aP[i] += wp.x*xv.x + wp.y*xv.y + wp.z*xv.z + wp.w*xv.w;
        }
    }
    const float bg = gbias[ci], bt = tbias[ci], bp = pbias[ci];
    #pragma unroll
    for (int i = 0; i < 8; ++i) {
        const size_t o = ((size_t)b * NHW + n0 + nh*8 + i) * CIO + ci;
        unsigned short h, l;
        splitbf(aT[i] + bt, h, l); th_hi[o] = h; th_lo[o] = l;
        splitbf(aP[i] + bp, h, l); ph_hi[o] = h; ph_lo[o] = l;
        g32[o] = aG[i] + bg;
    }
}

// ---------------------------------------------------------------------------
// K2: Z[m] = sum_n exp(f[n,m]-20), now on the r21-proven fine-grained
// pattern: 16 m-chunks of 400 (XCD = linear%8 = x%8), 16m tiles via f16c
// (bitwise-identical f0 chain to k_attn). Barrier-free -> uneven 25-tile
// round-robin over 4 waves is safe. Reduce over 16 n-lanes + atomicAdd.
// ---------------------------------------------------------------------------
__global__ __launch_bounds__(256) void k_colsum(
    const unsigned short* __restrict__ ph_hi, const unsigned short* __restrict__ ph_lo,
    const unsigned short* __restrict__ th_hi, const unsigned short* __restrict__ th_lo,
    float* __restrict__ Zp)
{
    const int mc = blockIdx.x * 400;    // 16 m-chunks; XCD = linear%8 = x%8
    const int n0 = blockIdx.y * 16;
    const int b  = blockIdx.z;
    const int w  = threadIdx.x >> 6;
    const int lane = threadIdx.x & 63;
    const int lm = lane & 15, kg = lane >> 4;
    bf16x8 tBh[4], tBl[4];
    {
        const size_t tb = ((size_t)b * NHW + n0 + lm) * CIO + kg * 8;
        #pragma unroll
        for (int kk = 0; kk < 4; ++kk) {
            tBh[kk] = *(const bf16x8*)(th_hi + tb + kk * 32);
            tBl[kk] = *(const bf16x8*)(th_lo + tb + kk * 32);
        }
    }
    for (int tt = w; tt < 25; tt += 4) {   // 25 tiles of 16m (no barrier)
        const int m0 = mc + tt * 16;
        const size_t a0 = ((size_t)b * NHW + m0 + lm) * CIO + kg * 8;
        f32x4 f0;
        f16c(ph_hi, ph_lo, a0, tBh, tBl, f0);
        #pragma unroll
        for (int j = 0; j < 4; ++j) {
            float v0 = pexp(f0[j]);
            v0 += __shfl_xor(v0, 1, 64); v0 += __shfl_xor(v0, 2, 64);
            v0 += __shfl_xor(v0, 4, 64); v0 += __shfl_xor(v0, 8, 64);
            if ((lane & 15) == 0)
                atomicAdd(&Zp[(size_t)b * NHW + m0 + kg*4 + j], v0);
        }
    }
}

// ---------------------------------------------------------------------------
// K3: y[n][c] = sum_m (exp(f[n,m]-20)/Z[m]) * g[m][c] — r21's validated
// barrier-free wave-private NT=2 structure, BYTE-IDENTICAL to r21 (16 chunks
// of 400m, 25 tiles, counted vmcnt, XCD-pinned). Frozen: r19 showed the
// counted-wait scheme is codegen-fragile outside this exact configuration.
// ---------------------------------------------------------------------------
__global__ __launch_bounds__(256) void k_attn(
    const unsigned short* __restrict__ ph_hi, const unsigned short* __restrict__ ph_lo,
    const unsigned short* __restrict__ th_hi, const unsigned short* __restrict__ th_lo,
    const float* __restrict__ g32, const float* __restrict__ Zp,
    float* __restrict__ yT)
{
    __shared__ float gl[4][2][8][32];   // [wave][dbuf][m][c] = 8 KB total
    const int mc = blockIdx.x * 400;    // 16 m-chunks; XCD = linear%8 = x%8
    const int n0 = blockIdx.y * 32;     // two 16-row n-tiles: n0, n0+16
    const int b  = blockIdx.z;
    const int w  = threadIdx.x >> 6;
    const int lane = threadIdx.x & 63;
    const int lm = lane & 15, kg = lane >> 4;
    const int cw = w * 32;              // wave's 32-channel window
    bf16x8 tAh[4], tAl[4], tCh[4], tCl[4];   // theta frags for both n-tiles
    {
        const size_t tba = ((size_t)b * NHW + n0 + lm) * CIO + kg * 8;
        const size_t tbc = tba + (size_t)16 * CIO;
        #pragma unroll
        for (int kk = 0; kk < 4; ++kk) {
            tAh[kk] = *(const bf16x8*)(th_hi + tba + kk * 32);
            tAl[kk] = *(const bf16x8*)(th_lo + tba + kk * 32);
            tCh[kk] = *(const bf16x8*)(th_hi + tbc + kk * 32);
            tCl[kk] = *(const bf16x8*)(th_lo + tbc + kk * 32);
        }
    }
    float acc0[8], acc1[8];
    #pragma unroll
    for (int i = 0; i < 8; ++i) { acc0[i] = 0.0f; acc1[i] = 0.0f; }

    // stage half k (8 m-rows): lane l -> row l>>3, col-chunk l&7 of the
    // wave's c-window; LDS implicit lane*16B matches [8][32] f32 layout.
    const float* gsrc = g32 + ((size_t)b * NHW + mc + (lane >> 3)) * CIO
                            + cw + (lane & 7) * 4;
    char* bufw = (char*)&gl[w][0][0][0];
    #define STAGE(k) gload16(gsrc + (size_t)(k) * 8 * CIO, bufw + ((k) & 1) * 1024)

    // prologue: stage halves 0,1; f(0)
    STAGE(0);
    STAGE(1);
    f32x4 f0a, f0c;
    {
        const size_t a0 = ((size_t)b * NHW + mc + lm) * CIO + kg * 8;
        f16c(ph_hi, ph_lo, a0, tAh, tAl, f0a);
        f16c(ph_hi, ph_lo, a0, tCh, tCl, f0c);
    }

    for (int t = 0; t < 25; ++t) {
        const int m0 = mc + t * 16;
        // preg(t): r14-exact P/Z (f-loads from end of t-1 retired here)
        const float* zb = Zp + (size_t)b * NHW + m0;
        float prega[4], pregc[4];
        #pragma unroll
        for (int j = 0; j < 4; ++j) {
            const float r = 1.0f / zb[kg*4 + j];
            prega[j] = pexp(f0a[j]) * r;
            pregc[j] = pexp(f0c[j]) * r;
        }
        // wait: outstanding = {stage(2t), stage(2t+1)} -> vmcnt(1) => 2t done
        asm volatile("s_waitcnt vmcnt(1)" ::: "memory");
        __builtin_amdgcn_sched_barrier(0);
        #pragma unroll
        for (int mi = 0; mi < 8; ++mi) {           // consume half 2t (mig=mi)
            const int kgp = mi >> 2, jp = mi & 3;
            const float psa = __shfl(prega[jp], lm + 16*kgp, 64);
            const float psc = __shfl(pregc[jp], lm + 16*kgp, 64);
            const float* gr = &gl[w][0][mi][kg * 8];
            float4 v0 = *(const float4*)(gr);
            float4 v1 = *(const float4*)(gr + 4);
            acc0[0] = __builtin_fmaf(psa, v0.x, acc0[0]);
            acc0[1] = __builtin_fmaf(psa, v0.y, acc0[1]);
            acc0[2] = __builtin_fmaf(psa, v0.z, acc0[2]);
            acc0[3] = __builtin_fmaf(psa, v0.w, acc0[3]);
            acc0[4] = __builtin_fmaf(psa, v1.x, acc0[4]);
            acc0[5] = __builtin_fmaf(psa, v1.y, acc0[5]);
            acc0[6] = __builtin_fmaf(psa, v1.z, acc0[6]);
            acc0[7] = __builtin_fmaf(psa, v1.w, acc0[7]);
            acc1[0] = __builtin_fmaf(psc, v0.x, acc1[0]);
            acc1[1] = __builtin_fmaf(psc, v0.y, acc1[1]);
            acc1[2] = __builtin_fmaf(psc, v0.z, acc1[2]);
            acc1[3] = __builtin_fmaf(psc, v0.w, acc1[3]);
            acc1[4] = __builtin_fmaf(psc, v1.x, acc1[4]);
            acc1[5] = __builtin_fmaf(psc, v1.y, acc1[5]);
            acc1[6] = __builtin_fmaf(psc, v1.z, acc1[6]);
            acc1[7] = __builtin_fmaf(psc, v1.w, acc1[7]);
        }
        if (t < 24) {
            STAGE(2*t + 2);
            // outstanding = {stage(2t+1), stage(2t+2)} -> vmcnt(1) => 2t+1 done
            asm volatile("s_waitcnt vmcnt(1)" ::: "memory");
        } else {
            asm volatile("s_waitcnt vmcnt(0)" ::: "memory");
        }
        __builtin_amdgcn_sched_barrier(0);
        #pragma unroll
        for (int mi = 0; mi < 8; ++mi) {           // consume half 2t+1 (mig=8+mi)
            const int mig = 8 + mi;
            const int kgp = mig >> 2, jp = mig & 3;
            const float psa = __shfl(prega[jp], lm + 16*kgp, 64);
            const float psc = __shfl(pregc[jp], lm + 16*kgp, 64);
            const float* gr = &gl[w][1][mi][kg * 8];
            float4 v0 = *(const float4*)(gr);
            float4 v1 = *(const float4*)(gr + 4);
            acc0[0] = __builtin_fmaf(psa, v0.x, acc0[0]);
            acc0[1] = __builtin_fmaf(psa, v0.y, acc0[1]);
            acc0[2] = __builtin_fmaf(psa, v0.z, acc0[2]);
            acc0[3] = __builtin_fmaf(psa, v0.w, acc0[3]);
            acc0[4] = __builtin_fmaf(psa, v1.x, acc0[4]);
            acc0[5] = __builtin_fmaf(psa, v1.y, acc0[5]);
            acc0[6] = __builtin_fmaf(psa, v1.z, acc0[6]);
            acc0[7] = __builtin_fmaf(psa, v1.w, acc0[7]);
            acc1[0] = __builtin_fmaf(psc, v0.x, acc1[0]);
            acc1[1] = __builtin_fmaf(psc, v0.y, acc1[1]);
            acc1[2] = __builtin_fmaf(psc, v0.z, acc1[2]);
            acc1[3] = __builtin_fmaf(psc, v0.w, acc1[3]);
            acc1[4] = __builtin_fmaf(psc, v1.x, acc1[4]);
            acc1[5] = __builtin_fmaf(psc, v1.y, acc1[5]);
            acc1[6] = __builtin_fmaf(psc, v1.z, acc1[6]);
            acc1[7] = __builtin_fmaf(psc, v1.w, acc1[7]);
        }
        if (t < 24) {
            STAGE(2*t + 3);
            // f(t+1): issued last so its 16 global loads retire during the
            // next iteration's preg, never between a STAGE and its wait.
            const size_t a0 = ((size_t)b * NHW + m0 + 16 + lm) * CIO + kg * 8;
            f16c(ph_hi, ph_lo, a0, tAh, tAl, f0a);
            f16c(ph_hi, ph_lo, a0, tCh, tCl, f0c);
        }
    }
    #undef STAGE
    // epilogue: lane owns (n0+lm, cw+kg*8+i) and (n0+16+lm, cw+kg*8+i)
    #pragma unroll
    for (int i = 0; i < 8; ++i) {
        atomicAdd(&yT[((size_t)b * CIO + cw + kg*8 + i) * NHW + n0 + lm], acc0[i]);
        atomicAdd(&yT[((size_t)b * CIO + cw + kg*8 + i) * NHW + n0 + 16 + lm], acc1[i]);
    }
}

// ---------------------------------------------------------------------------
// K3b: W transpose fp32: WT[ci][co] (overlays g32; launched after k_attn)
// ---------------------------------------------------------------------------
__global__ __launch_bounds__(256) void k_wT(
    const float* __restrict__ Ww, float* __restrict__ WT)
{
    const int i = blockIdx.x * 256 + threadIdx.x;   // grid covers 32768
    const int co = i >> 7, ci = i & 127;
    WT[(size_t)ci * CIN + co] = Ww[(size_t)co * CIO + ci];
}

// ---------------------------------------------------------------------------
// K4: out[b][co][n] = x + W_b[co] + sum_ci WT[ci][co] * y[ci][n], fp32 VALU
// (validated r6/r11/r13). Block = 16 n, 256 threads = 256 co; y in LDS.
// ---------------------------------------------------------------------------
__global__ __launch_bounds__(256) void k_out(
    const float* __restrict__ yT, const float* __restrict__ WT,
    const float* __restrict__ Wbias, const float* __restrict__ x,
    float* __restrict__ out)
{
    __shared__ float yl[128][20];
    const int n0 = blockIdx.x * 16;
    const int b  = blockIdx.y;
    const int t  = threadIdx.x;
    {
        const int c = t >> 1, nh = (t & 1) * 8;
        const float* yp = yT + ((size_t)b * CIO + c) * NHW + n0 + nh;
        float4 v0 = *(const float4*)(yp);
        float4 v1 = *(const float4*)(yp + 4);
        yl[c][nh+0] = v0.x; yl[c][nh+1] = v0.y; yl[c][nh+2] = v0.z; yl[c][nh+3] = v0.w;
        yl[c][nh+4] = v1.x; yl[c][nh+5] = v1.y; yl[c][nh+6] = v1.z; yl[c][nh+7] = v1.w;
    }
    __syncthreads();
    const int co = t;
    float acc[16];
    #pragma unroll
    for (int i = 0; i < 16; ++i) acc[i] = 0.0f;
    for (int ci = 0; ci < CIO; ++ci) {
        const float wv = WT[(size_t)ci * CIN + co];
        const float4 y0 = *(const float4*)&yl[ci][0];
        const float4 y1 = *(const float4*)&yl[ci][4];
        const float4 y2 = *(const float4*)&yl[ci][8];
        const float4 y3 = *(const float4*)&yl[ci][12];
        acc[0]  = __builtin_fmaf(wv, y0.x, acc[0]);
        acc[1]  = __builtin_fmaf(wv, y0.y, acc[1]);
        acc[2]  = __builtin_fmaf(wv, y0.z, acc[2]);
        acc[3]  = __builtin_fmaf(wv, y0.w, acc[3]);
        acc[4]  = __builtin_fmaf(wv, y1.x, acc[4]);
        acc[5]  = __builtin_fmaf(wv, y1.y, acc[5]);
        acc[6]  = __builtin_fmaf(wv, y1.z, acc[6]);
        acc[7]  = __builtin_fmaf(wv, y1.w, acc[7]);
        acc[8]  = __builtin_fmaf(wv, y2.x, acc[8]);
        acc[9]  = __builtin_fmaf(wv, y2.y, acc[9]);
        acc[10] = __builtin_fmaf(wv, y2.z, acc[10]);
        acc[11] = __builtin_fmaf(wv, y2.w, acc[11]);
        acc[12] = __builtin_fmaf(wv, y3.x, acc[12]);
        acc[13] = __builtin_fmaf(wv, y3.y, acc[13]);
        acc[14] = __builtin_fmaf(wv, y3.z, acc[14]);
        acc[15] = __builtin_fmaf(wv, y3.w, acc[15]);
    }
    const float wb = Wbias[co];
    const size_t ob = ((size_t)b * CIN + co) * NHW + n0;
    #pragma unroll
    for (int q = 0; q < 4; ++q) {
        float4 xv = *(const float4*)&x[ob + q*4];
        float4 ov;
        ov.x = acc[q*4+0] + xv.x + wb;
        ov.y = acc[q*4+1] + xv.y + wb;
        ov.z = acc[q*4+2] + xv.z + wb;
        ov.w = acc[q*4+3] + xv.w + wb;
        *(float4*)&out[ob + q*4] = ov;
    }
}

extern "C" void kernel_launch(void* const* d_in, const int* in_sizes, int n_in,
                              void* d_out, int out_size, void* d_ws, size_t ws_size,
                              hipStream_t stream)
{
    const float* x     = (const float*)d_in[0];
    const float* gw    = (const float*)d_in[1];
    const float* gbias = (const float*)d_in[2];
    const float* tw    = (const float*)d_in[3];
    const float* tbias = (const float*)d_in[4];
    const float* pw    = (const float*)d_in[5];
    const float* pbias = (const float*)d_in[6];
    const float* Ww    = (const float*)d_in[7];
    const float* Wbias = (const float*)d_in[8];

    // theta/phi split planes in d_out (scratch until k_out rewrites it):
    // 4 x 3,276,800 B == out bytes exactly.
    char* ob = (char*)d_out;
    const size_t SZ = (size_t)NB * NHW * CIO * 2;   // 3,276,800 B
    unsigned short* th_hi = (unsigned short*)(ob);
    unsigned short* th_lo = (unsigned short*)(ob + SZ);
    unsigned short* ph_hi = (unsigned short*)(ob + 2*SZ);
    unsigned short* ph_lo = (unsigned short*)(ob + 3*SZ);

    // ws: 13,158,400 B total (r5/r11/r13-proven footprint)
    char* ws = (char*)d_ws;
    const size_t SZF = (size_t)NB * NHW * CIO * 4;   // 6,553,600 B
    float* g32 = (float*)(ws);               // dead after k_attn
    float* WT  = (float*)(ws);               // overlays g32 (k_wT after k_attn)
    float* yT  = (float*)(ws + SZF);
    float* Zp  = (float*)(ws + 2*SZF);       // 51,200 B
    float* out = (float*)d_out;

    k_zero  <<<dim3(50),         256, 0, stream>>>(Zp);
    k_zeroy <<<dim3(1600),       256, 0, stream>>>(yT);
    k_proj  <<<dim3(400, 2),     256, 0, stream>>>(x, gw, gbias, tw, tbias, pw, pbias,
                                                   th_hi, th_lo, ph_hi, ph_lo, g32);
    k_colsum<<<dim3(16, 400, 2), 256, 0, stream>>>(ph_hi, ph_lo, th_hi, th_lo, Zp);
    k_attn  <<<dim3(16, 200, 2), 256, 0, stream>>>(ph_hi, ph_lo, th_hi, th_lo, g32, Zp, yT);
    k_wT    <<<dim3(128),        256, 0, stream>>>(Ww, WT);
    k_out   <<<dim3(400, 2),     256, 0, stream>>>(yT, WT, Wbias, x, out);
}

// Round 23
// 1697.735 us; speedup vs baseline: 1.0263x; 1.0263x over previous
//
#include <hip/hip_runtime.h>
#include <hip/hip_bf16.h>

#define NHW 6400
#define CIN 256
#define CIO 128
#define NB 2

typedef __bf16 bf16x8 __attribute__((ext_vector_type(8)));
typedef float f32x4 __attribute__((ext_vector_type(4)));

#define LOG2E 1.4426950408889634f
#define FSH (-20.0f * LOG2E)   // fixed logit shift, cancels exactly in softmax ratio

__device__ __forceinline__ unsigned short f2bfu(float x) {
    union { float f; unsigned u; } a; a.f = x;
    unsigned r = (a.u + 0x7fffu + ((a.u >> 16) & 1u)) >> 16;  // RNE
    return (unsigned short)r;
}
__device__ __forceinline__ float bfu2f(unsigned short v) {
    union { unsigned u; float f; } a; a.u = ((unsigned)v) << 16;
    return a.f;
}
__device__ __forceinline__ void splitbf(float v, unsigned short& h, unsigned short& l) {
    unsigned short hh = f2bfu(v);
    h = hh;
    l = f2bfu(v - bfu2f(hh));
}
// identical exp path in both passes: v_fma_f32 + v_exp_f32
__device__ __forceinline__ float pexp(float f) {
    return __builtin_amdgcn_exp2f(__builtin_fmaf(f, LOG2E, FSH));
}

#define MFMA(a, b, c) __builtin_amdgcn_mfma_f32_16x16x32_bf16((a), (b), (c), 0, 0, 0)

// async global->LDS, 16B per lane: per-lane global src, wave-uniform LDS base
typedef const __attribute__((address_space(1))) unsigned gu32;
typedef __attribute__((address_space(3))) unsigned lu32;
__device__ __forceinline__ void gload16(const void* g, void* l) {
    __builtin_amdgcn_global_load_lds((gu32*)g, (lu32*)l, 16, 0, 0);
}

// Full f-tile (32m x 16n) — used by k_colsum (validated r6/r11/r13).
__device__ __forceinline__ void f_tile(
    const unsigned short* __restrict__ ph_hi, const unsigned short* __restrict__ ph_lo,
    size_t a0, size_t a1, const bf16x8* tBh, const bf16x8* tBl,
    f32x4& f0, f32x4& f1)
{
    const f32x4 z4 = {0.f, 0.f, 0.f, 0.f};
    f0 = z4; f1 = z4;
    #pragma unroll
    for (int kk = 0; kk < 4; ++kk) {
        bf16x8 Ah0 = *(const bf16x8*)(ph_hi + a0 + kk*32);
        bf16x8 Al0 = *(const bf16x8*)(ph_lo + a0 + kk*32);
        bf16x8 Ah1 = *(const bf16x8*)(ph_hi + a1 + kk*32);
        bf16x8 Al1 = *(const bf16x8*)(ph_lo + a1 + kk*32);
        f0 = MFMA(Ah0, tBh[kk], f0);
        f0 = MFMA(Ah0, tBl[kk], f0);
        f0 = MFMA(Al0, tBh[kk], f0);
        f1 = MFMA(Ah1, tBh[kk], f1);
        f1 = MFMA(Ah1, tBl[kk], f1);
        f1 = MFMA(Al1, tBh[kk], f1);
    }
}

// 16m f-chain — BITWISE identical to f_tile's f0 chain (same op sequence),
// so k_attn's logits match k_colsum's exactly for any 16-aligned m0.
__device__ __forceinline__ void f16c(
    const unsigned short* __restrict__ ph_hi, const unsigned short* __restrict__ ph_lo,
    size_t a0, const bf16x8* tBh, const bf16x8* tBl, f32x4& f0)
{
    const f32x4 z4 = {0.f, 0.f, 0.f, 0.f};
    f0 = z4;
    #pragma unroll
    for (int kk = 0; kk < 4; ++kk) {
        bf16x8 Ah0 = *(const bf16x8*)(ph_hi + a0 + kk*32);
        bf16x8 Al0 = *(const bf16x8*)(ph_lo + a0 + kk*32);
        f0 = MFMA(Ah0, tBh[kk], f0);
        f0 = MFMA(Ah0, tBl[kk], f0);
        f0 = MFMA(Al0, tBh[kk], f0);
    }
}

// ---------------------------------------------------------------------------
// K0: zero Z
// ---------------------------------------------------------------------------
__global__ __launch_bounds__(256) void k_zero(float* __restrict__ Zp) {
    const int i = blockIdx.x * 256 + threadIdx.x;
    if (i < NB * NHW) Zp[i] = 0.0f;
}
// K0b: zero yT (atomic accumulation target)
__global__ __launch_bounds__(256) void k_zeroy(float* __restrict__ yT) {
    const size_t i = (size_t)blockIdx.x * 256 + threadIdx.x;  // covers NB*CIO*NHW/4
    float4 z = {0.f, 0.f, 0.f, 0.f};
    *(float4*)&yT[i * 4] = z;
}

// ---------------------------------------------------------------------------
// K1: three 1x1-conv projections (fp32 VALU, validated r5/r6/r11). theta/phi
// -> split-bf16 planes [b][n][ci] (carved from d_out); g -> fp32 [b][m][ci].
// ---------------------------------------------------------------------------
__global__ __launch_bounds__(256) void k_proj(
    const float* __restrict__ x,
    const float* __restrict__ gw, const float* __restrict__ gbias,
    const float* __restrict__ tw, const float* __restrict__ tbias,
    const float* __restrict__ pw, const float* __restrict__ pbias,
    unsigned short* __restrict__ th_hi, unsigned short* __restrict__ th_lo,
    unsigned short* __restrict__ ph_hi, unsigned short* __restrict__ ph_lo,
    float* __restrict__ g32)
{
    __shared__ float xT[16][260];
    const int n0 = blockIdx.x * 16;
    const int b  = blockIdx.y;
    const int t  = threadIdx.x;
    {
        const int nq = t & 3, cq = t >> 2;
        #pragma unroll
        for (int c0 = 0; c0 < 4; ++c0) {
            const int c = c0 * 64 + cq;
            float4 v = *(const float4*)&x[((size_t)b * CIN + c) * NHW + n0 + nq * 4];
            xT[nq*4+0][c] = v.x; xT[nq*4+1][c] = v.y;
            xT[nq*4+2][c] = v.z; xT[nq*4+3][c] = v.w;
        }
    }
    __syncthreads();
    const int ci = t & 127, nh = t >> 7;
    float aG[8], aT[8], aP[8];
    #pragma unroll
    for (int i = 0; i < 8; ++i) { aG[i]=0.f; aT[i]=0.f; aP[i]=0.f; }
    for (int c4 = 0; c4 < 64; ++c4) {
        float4 wg = *(const float4*)&gw[ci*CIN + c4*4];
        float4 wt = *(const float4*)&tw[ci*CIN + c4*4];
        float4 wp = *(const float4*)&pw[ci*CIN + c4*4];
        #pragma unroll
        for (int i = 0; i < 8; ++i) {
            float4 xv = *(const float4*)&xT[nh*8 + i][c4*4];
            aG[i] += wg.x*xv.x + wg.y*xv.y + wg.z*xv.z + wg.w*xv.w;
            aT[i] += wt.x*xv.x + wt.y*xv.y + wt.z*xv.z + wt.w*xv.w;
            aP[i] += wp.x*xv.x + wp.y*xv.y + wp.z*xv.z + wp.w*xv.w;
        }
    }
    const float bg = gbias[ci], bt = tbias[ci], bp = pbias[ci];
    #pragma unroll
    for (int i = 0; i < 8; ++i) {
        const size_t o = ((size_t)b * NHW + n0 + nh*8 + i) * CIO + ci;
        unsigned short h, l;
        splitbf(aT[i] + bt, h, l); th_hi[o] = h; th_lo[o] = l;
        splitbf(aP[i] + bp, h, l); ph_hi[o] = h; ph_lo[o] = l;
        g32[o] = aG[i] + bg;
    }
}

// ---------------------------------------------------------------------------
// K2: Z[m] = sum_n exp(f[n,m]-20) via shared f_tile (r11/r13-validated math).
// XCD-pinned (r18): m-chunk in blockIdx.x -> linear%8 = chunk.
// ---------------------------------------------------------------------------
__global__ __launch_bounds__(256) void k_colsum(
    const unsigned short* __restrict__ ph_hi, const unsigned short* __restrict__ ph_lo,
    const unsigned short* __restrict__ th_hi, const unsigned short* __restrict__ th_lo,
    float* __restrict__ Zp)
{
    const int mc = blockIdx.x * 800;    // 8 m-chunks -> XCD = linear%8 = x
    const int n0 = blockIdx.y * 16;
    const int b  = blockIdx.z;
    const int w  = threadIdx.x >> 6;
    const int lane = threadIdx.x & 63;
    const int lm = lane & 15, kg = lane >> 4;
    bf16x8 tBh[4], tBl[4];
    {
        const size_t tb = ((size_t)b * NHW + n0 + lm) * CIO + kg * 8;
        #pragma unroll
        for (int kk = 0; kk < 4; ++kk) {
            tBh[kk] = *(const bf16x8*)(th_hi + tb + kk * 32);
            tBl[kk] = *(const bf16x8*)(th_lo + tb + kk * 32);
        }
    }
    for (int tt = w; tt < 25; tt += 4) {   // 25 tiles of 32m
        const int m0 = mc + tt * 32;
        const size_t a0 = ((size_t)b * NHW + m0 + lm) * CIO + kg * 8;
        const size_t a1 = a0 + (size_t)16 * CIO;
        f32x4 f0, f1;
        f_tile(ph_hi, ph_lo, a0, a1, tBh, tBl, f0, f1);
        #pragma unroll
        for (int j = 0; j < 4; ++j) {
            float v0 = pexp(f0[j]);
            v0 += __shfl_xor(v0, 1, 64); v0 += __shfl_xor(v0, 2, 64);
            v0 += __shfl_xor(v0, 4, 64); v0 += __shfl_xor(v0, 8, 64);
            float v1 = pexp(f1[j]);
            v1 += __shfl_xor(v1, 1, 64); v1 += __shfl_xor(v1, 2, 64);
            v1 += __shfl_xor(v1, 4, 64); v1 += __shfl_xor(v1, 8, 64);
            if ((lane & 15) == 0) {
                atomicAdd(&Zp[(size_t)b * NHW + m0 + kg*4 + j], v0);
                atomicAdd(&Zp[(size_t)b * NHW + m0 + 16 + kg*4 + j], v1);
            }
        }
    }
}

// ---------------------------------------------------------------------------
// K3: y[n][c] = sum_m (exp(f[n,m]-20)/Z[m]) * g[m][c] — r18/r20's validated
// barrier-free wave-private NT=2 structure, inner loop BYTE-IDENTICAL; only
// the m-split granularity changes: 16 chunks of 400 m (25 tiles/block,
// 6400 blocks of ~55 us) for finer scheduling + tail amortization
// (4.2 -> 8.3 rounds/CU). XCD locality preserved: chunks c and c+8 share
// XCD c%8; hot slice 2x410KB phi + 2x205KB g fits 4MB L2.
// ---------------------------------------------------------------------------
__global__ __launch_bounds__(256) void k_attn(
    const unsigned short* __restrict__ ph_hi, const unsigned short* __restrict__ ph_lo,
    const unsigned short* __restrict__ th_hi, const unsigned short* __restrict__ th_lo,
    const float* __restrict__ g32, const float* __restrict__ Zp,
    float* __restrict__ yT)
{
    __shared__ float gl[4][2][8][32];   // [wave][dbuf][m][c] = 8 KB total
    const int mc = blockIdx.x * 400;    // 16 m-chunks; XCD = linear%8 = x%8
    const int n0 = blockIdx.y * 32;     // two 16-row n-tiles: n0, n0+16
    const int b  = blockIdx.z;
    const int w  = threadIdx.x >> 6;
    const int lane = threadIdx.x & 63;
    const int lm = lane & 15, kg = lane >> 4;
    const int cw = w * 32;              // wave's 32-channel window
    bf16x8 tAh[4], tAl[4], tCh[4], tCl[4];   // theta frags for both n-tiles
    {
        const size_t tba = ((size_t)b * NHW + n0 + lm) * CIO + kg * 8;
        const size_t tbc = tba + (size_t)16 * CIO;
        #pragma unroll
        for (int kk = 0; kk < 4; ++kk) {
            tAh[kk] = *(const bf16x8*)(th_hi + tba + kk * 32);
            tAl[kk] = *(const bf16x8*)(th_lo + tba + kk * 32);
            tCh[kk] = *(const bf16x8*)(th_hi + tbc + kk * 32);
            tCl[kk] = *(const bf16x8*)(th_lo + tbc + kk * 32);
        }
    }
    float acc0[8], acc1[8];
    #pragma unroll
    for (int i = 0; i < 8; ++i) { acc0[i] = 0.0f; acc1[i] = 0.0f; }

    // stage half k (8 m-rows): lane l -> row l>>3, col-chunk l&7 of the
    // wave's c-window; LDS implicit lane*16B matches [8][32] f32 layout.
    const float* gsrc = g32 + ((size_t)b * NHW + mc + (lane >> 3)) * CIO
                            + cw + (lane & 7) * 4;
    char* bufw = (char*)&gl[w][0][0][0];
    #define STAGE(k) gload16(gsrc + (size_t)(k) * 8 * CIO, bufw + ((k) & 1) * 1024)

    // prologue: stage halves 0,1; f(0)
    STAGE(0);
    STAGE(1);
    f32x4 f0a, f0c;
    {
        const size_t a0 = ((size_t)b * NHW + mc + lm) * CIO + kg * 8;
        f16c(ph_hi, ph_lo, a0, tAh, tAl, f0a);
        f16c(ph_hi, ph_lo, a0, tCh, tCl, f0c);
    }

    for (int t = 0; t < 25; ++t) {
        const int m0 = mc + t * 16;
        // preg(t): r14-exact P/Z (f-loads from end of t-1 retired here)
        const float* zb = Zp + (size_t)b * NHW + m0;
        float prega[4], pregc[4];
        #pragma unroll
        for (int j = 0; j < 4; ++j) {
            const float r = 1.0f / zb[kg*4 + j];
            prega[j] = pexp(f0a[j]) * r;
            pregc[j] = pexp(f0c[j]) * r;
        }
        // wait: outstanding = {stage(2t), stage(2t+1)} -> vmcnt(1) => 2t done
        asm volatile("s_waitcnt vmcnt(1)" ::: "memory");
        __builtin_amdgcn_sched_barrier(0);
        #pragma unroll
        for (int mi = 0; mi < 8; ++mi) {           // consume half 2t (mig=mi)
            const int kgp = mi >> 2, jp = mi & 3;
            const float psa = __shfl(prega[jp], lm + 16*kgp, 64);
            const float psc = __shfl(pregc[jp], lm + 16*kgp, 64);
            const float* gr = &gl[w][0][mi][kg * 8];
            float4 v0 = *(const float4*)(gr);
            float4 v1 = *(const float4*)(gr + 4);
            acc0[0] = __builtin_fmaf(psa, v0.x, acc0[0]);
            acc0[1] = __builtin_fmaf(psa, v0.y, acc0[1]);
            acc0[2] = __builtin_fmaf(psa, v0.z, acc0[2]);
            acc0[3] = __builtin_fmaf(psa, v0.w, acc0[3]);
            acc0[4] = __builtin_fmaf(psa, v1.x, acc0[4]);
            acc0[5] = __builtin_fmaf(psa, v1.y, acc0[5]);
            acc0[6] = __builtin_fmaf(psa, v1.z, acc0[6]);
            acc0[7] = __builtin_fmaf(psa, v1.w, acc0[7]);
            acc1[0] = __builtin_fmaf(psc, v0.x, acc1[0]);
            acc1[1] = __builtin_fmaf(psc, v0.y, acc1[1]);
            acc1[2] = __builtin_fmaf(psc, v0.z, acc1[2]);
            acc1[3] = __builtin_fmaf(psc, v0.w, acc1[3]);
            acc1[4] = __builtin_fmaf(psc, v1.x, acc1[4]);
            acc1[5] = __builtin_fmaf(psc, v1.y, acc1[5]);
            acc1[6] = __builtin_fmaf(psc, v1.z, acc1[6]);
            acc1[7] = __builtin_fmaf(psc, v1.w, acc1[7]);
        }
        if (t < 24) {
            STAGE(2*t + 2);
            // outstanding = {stage(2t+1), stage(2t+2)} -> vmcnt(1) => 2t+1 done
            asm volatile("s_waitcnt vmcnt(1)" ::: "memory");
        } else {
            asm volatile("s_waitcnt vmcnt(0)" ::: "memory");
        }
        __builtin_amdgcn_sched_barrier(0);
        #pragma unroll
        for (int mi = 0; mi < 8; ++mi) {           // consume half 2t+1 (mig=8+mi)
            const int mig = 8 + mi;
            const int kgp = mig >> 2, jp = mig & 3;
            const float psa = __shfl(prega[jp], lm + 16*kgp, 64);
            const float psc = __shfl(pregc[jp], lm + 16*kgp, 64);
            const float* gr = &gl[w][1][mi][kg * 8];
            float4 v0 = *(const float4*)(gr);
            float4 v1 = *(const float4*)(gr + 4);
            acc0[0] = __builtin_fmaf(psa, v0.x, acc0[0]);
            acc0[1] = __builtin_fmaf(psa, v0.y, acc0[1]);
            acc0[2] = __builtin_fmaf(psa, v0.z, acc0[2]);
            acc0[3] = __builtin_fmaf(psa, v0.w, acc0[3]);
            acc0[4] = __builtin_fmaf(psa, v1.x, acc0[4]);
            acc0[5] = __builtin_fmaf(psa, v1.y, acc0[5]);
            acc0[6] = __builtin_fmaf(psa, v1.z, acc0[6]);
            acc0[7] = __builtin_fmaf(psa, v1.w, acc0[7]);
            acc1[0] = __builtin_fmaf(psc, v0.x, acc1[0]);
            acc1[1] = __builtin_fmaf(psc, v0.y, acc1[1]);
            acc1[2] = __builtin_fmaf(psc, v0.z, acc1[2]);
            acc1[3] = __builtin_fmaf(psc, v0.w, acc1[3]);
            acc1[4] = __builtin_fmaf(psc, v1.x, acc1[4]);
            acc1[5] = __builtin_fmaf(psc, v1.y, acc1[5]);
            acc1[6] = __builtin_fmaf(psc, v1.z, acc1[6]);
            acc1[7] = __builtin_fmaf(psc, v1.w, acc1[7]);
        }
        if (t < 24) {
            STAGE(2*t + 3);
            // f(t+1): issued last so its 16 global loads retire during the
            // next iteration's preg, never between a STAGE and its wait.
            const size_t a0 = ((size_t)b * NHW + m0 + 16 + lm) * CIO + kg * 8;
            f16c(ph_hi, ph_lo, a0, tAh, tAl, f0a);
            f16c(ph_hi, ph_lo, a0, tCh, tCl, f0c);
        }
    }
    #undef STAGE
    // epilogue: lane owns (n0+lm, cw+kg*8+i) and (n0+16+lm, cw+kg*8+i)
    #pragma unroll
    for (int i = 0; i < 8; ++i) {
        atomicAdd(&yT[((size_t)b * CIO + cw + kg*8 + i) * NHW + n0 + lm], acc0[i]);
        atomicAdd(&yT[((size_t)b * CIO + cw + kg*8 + i) * NHW + n0 + 16 + lm], acc1[i]);
    }
}

// ---------------------------------------------------------------------------
// K3b: W transpose fp32: WT[ci][co] (overlays g32; launched after k_attn)
// ---------------------------------------------------------------------------
__global__ __launch_bounds__(256) void k_wT(
    const float* __restrict__ Ww, float* __restrict__ WT)
{
    const int i = blockIdx.x * 256 + threadIdx.x;   // grid covers 32768
    const int co = i >> 7, ci = i & 127;
    WT[(size_t)ci * CIN + co] = Ww[(size_t)co * CIO + ci];
}

// ---------------------------------------------------------------------------
// K4: out[b][co][n] = x + W_b[co] + sum_ci WT[ci][co] * y[ci][n], fp32 VALU
// (validated r6/r11/r13). Block = 16 n, 256 threads = 256 co; y in LDS.
// ---------------------------------------------------------------------------
__global__ __launch_bounds__(256) void k_out(
    const float* __restrict__ yT, const float* __restrict__ WT,
    const float* __restrict__ Wbias, const float* __restrict__ x,
    float* __restrict__ out)
{
    __shared__ float yl[128][20];
    const int n0 = blockIdx.x * 16;
    const int b  = blockIdx.y;
    const int t  = threadIdx.x;
    {
        const int c = t >> 1, nh = (t & 1) * 8;
        const float* yp = yT + ((size_t)b * CIO + c) * NHW + n0 + nh;
        float4 v0 = *(const float4*)(yp);
        float4 v1 = *(const float4*)(yp + 4);
        yl[c][nh+0] = v0.x; yl[c][nh+1] = v0.y; yl[c][nh+2] = v0.z; yl[c][nh+3] = v0.w;
        yl[c][nh+4] = v1.x; yl[c][nh+5] = v1.y; yl[c][nh+6] = v1.z; yl[c][nh+7] = v1.w;
    }
    __syncthreads();
    const int co = t;
    float acc[16];
    #pragma unroll
    for (int i = 0; i < 16; ++i) acc[i] = 0.0f;
    for (int ci = 0; ci < CIO; ++ci) {
        const float wv = WT[(size_t)ci * CIN + co];
        const float4 y0 = *(const float4*)&yl[ci][0];
        const float4 y1 = *(const float4*)&yl[ci][4];
        const float4 y2 = *(const float4*)&yl[ci][8];
        const float4 y3 = *(const float4*)&yl[ci][12];
        acc[0]  = __builtin_fmaf(wv, y0.x, acc[0]);
        acc[1]  = __builtin_fmaf(wv, y0.y, acc[1]);
        acc[2]  = __builtin_fmaf(wv, y0.z, acc[2]);
        acc[3]  = __builtin_fmaf(wv, y0.w, acc[3]);
        acc[4]  = __builtin_fmaf(wv, y1.x, acc[4]);
        acc[5]  = __builtin_fmaf(wv, y1.y, acc[5]);
        acc[6]  = __builtin_fmaf(wv, y1.z, acc[6]);
        acc[7]  = __builtin_fmaf(wv, y1.w, acc[7]);
        acc[8]  = __builtin_fmaf(wv, y2.x, acc[8]);
        acc[9]  = __builtin_fmaf(wv, y2.y, acc[9]);
        acc[10] = __builtin_fmaf(wv, y2.z, acc[10]);
        acc[11] = __builtin_fmaf(wv, y2.w, acc[11]);
        acc[12] = __builtin_fmaf(wv, y3.x, acc[12]);
        acc[13] = __builtin_fmaf(wv, y3.y, acc[13]);
        acc[14] = __builtin_fmaf(wv, y3.z, acc[14]);
        acc[15] = __builtin_fmaf(wv, y3.w, acc[15]);
    }
    const float wb = Wbias[co];
    const size_t ob = ((size_t)b * CIN + co) * NHW + n0;
    #pragma unroll
    for (int q = 0; q < 4; ++q) {
        float4 xv = *(const float4*)&x[ob + q*4];
        float4 ov;
        ov.x = acc[q*4+0] + xv.x + wb;
        ov.y = acc[q*4+1] + xv.y + wb;
        ov.z = acc[q*4+2] + xv.z + wb;
        ov.w = acc[q*4+3] + xv.w + wb;
        *(float4*)&out[ob + q*4] = ov;
    }
}

extern "C" void kernel_launch(void* const* d_in, const int* in_sizes, int n_in,
                              void* d_out, int out_size, void* d_ws, size_t ws_size,
                              hipStream_t stream)
{
    const float* x     = (const float*)d_in[0];
    const float* gw    = (const float*)d_in[1];
    const float* gbias = (const float*)d_in[2];
    const float* tw    = (const float*)d_in[3];
    const float* tbias = (const float*)d_in[4];
    const float* pw    = (const float*)d_in[5];
    const float* pbias = (const float*)d_in[6];
    const float* Ww    = (const float*)d_in[7];
    const float* Wbias = (const float*)d_in[8];

    // theta/phi split planes in d_out (scratch until k_out rewrites it):
    // 4 x 3,276,800 B == out bytes exactly.
    char* ob = (char*)d_out;
    const size_t SZ = (size_t)NB * NHW * CIO * 2;   // 3,276,800 B
    unsigned short* th_hi = (unsigned short*)(ob);
    unsigned short* th_lo = (unsigned short*)(ob + SZ);
    unsigned short* ph_hi = (unsigned short*)(ob + 2*SZ);
    unsigned short* ph_lo = (unsigned short*)(ob + 3*SZ);

    // ws: 13,158,400 B total (r5/r11/r13-proven footprint)
    char* ws = (char*)d_ws;
    const size_t SZF = (size_t)NB * NHW * CIO * 4;   // 6,553,600 B
    float* g32 = (float*)(ws);               // dead after k_attn
    float* WT  = (float*)(ws);               // overlays g32 (k_wT after k_attn)
    float* yT  = (float*)(ws + SZF);
    float* Zp  = (float*)(ws + 2*SZF);       // 51,200 B
    float* out = (float*)d_out;

    k_zero  <<<dim3(50),         256, 0, stream>>>(Zp);
    k_zeroy <<<dim3(1600),       256, 0, stream>>>(yT);
    k_proj  <<<dim3(400, 2),     256, 0, stream>>>(x, gw, gbias, tw, tbias, pw, pbias,
                                                   th_hi, th_lo, ph_hi, ph_lo, g32);
    k_colsum<<<dim3(8, 400, 2),  256, 0, stream>>>(ph_hi, ph_lo, th_hi, th_lo, Zp);
    k_attn  <<<dim3(16, 200, 2), 256, 0, stream>>>(ph_hi, ph_lo, th_hi, th_lo, g32, Zp, yT);
    k_wT    <<<dim3(128),        256, 0, stream>>>(Ww, WT);
    k_out   <<<dim3(400, 2),     256, 0, stream>>>(yT, WT, Wbias, x, out);
}